// Round 6
// baseline (1382.501 us; speedup 1.0000x reference)
//
#include <hip/hip_runtime.h>

#define BB 128
#define TT 2048
#define II 64
#define HH 128

typedef _Float16 h2 __attribute__((ext_vector_type(2)));
typedef _Float16 f16x8 __attribute__((ext_vector_type(8)));
typedef float f32x4 __attribute__((ext_vector_type(4)));

__device__ __forceinline__ h2 mkh2(float a, float b) {
    h2 r; r.x = (_Float16)a; r.y = (_Float16)b; return r;
}

__device__ __forceinline__ float rcp_fast(float x) {
    return __builtin_amdgcn_rcpf(x);
}

__device__ __forceinline__ float tanh_fast(float x) {
    return fmaf(rcp_fast(1.0f + __expf(-2.0f * x)), 2.0f, -1.0f);
}

__device__ __forceinline__ float sigmoid_fast(float x) {
    return rcp_fast(1.0f + __expf(-x));
}

__device__ __forceinline__ f16x8 ld_frag(const void* p) {
    return __builtin_bit_cast(f16x8, *reinterpret_cast<const uint4*>(p));
}

// One workgroup per batch element; 512 threads (8 waves), grid = 128 blocks.
//
// Matvec on the MATRIX pipe, software-pipelined:
//   critical path per step: W_hh*h only (16 MFMAs/wave, K-tiles of h).
//   W_ih*x_{t+1} (8 MFMAs/wave) issues AFTER the accumulator select of step
//   t, reusing the acc registers, overlapping the activation transcendental
//   chain. x is staged 2 steps ahead into a mod-3 LDS ring so x_{t+1} is
//   readable without waiting on the current step's barrier.
// Layouts (16x16x32_f16, validated r5): A row=lane&15, k=8*(lane>>4)+i;
//   B col=lane&15 (16-way broadcast), same k; D col=lane&15,
//   row=4*(lane>>4)+reg. Lane (w,grp,r) owns j = 16w+4*grp+r.
__global__ __launch_bounds__(512, 2) void lstm_fused_kernel(
    const float* __restrict__ input,  // [B,T,I]
    const float* __restrict__ h0,     // [B,H]
    const float* __restrict__ c0,     // [B,H]
    const float* __restrict__ W_ih,   // [4H,I]
    const float* __restrict__ W_hh,   // [4H,H]
    const float* __restrict__ b_ih,   // [4H]
    const float* __restrict__ b_hh,   // [4H]
    float* __restrict__ out)          // [B*H] h_last, then [B,T,H] encoded
{
    __shared__ __align__(16) h2 s_x[3][II / 2];   // x ring: staged t+2, read t+1
    __shared__ __align__(16) h2 s_h[2][HH / 2];   // h double buffer

    const int tid  = threadIdx.x;
    const int b    = blockIdx.x;
    const int lane = tid & 63;
    const int w    = tid >> 6;          // wave 0..7
    const int grp  = lane >> 4;         // k-group / D-row-group
    const int m    = lane & 15;         // A row within tile / D col
    const int r    = lane & 3;          // selected accumulator element
    const int jown = (w << 4) | (grp << 2) | r;   // owned h element

    // ---- A-fragments: W_ih (2 K-tiles) + W_hh (4 K-tiles), fp32 -> fp16 ----
    f16x8 wfx[4][2];   // 32 VGPR
    f16x8 wfh[4][4];   // 64 VGPR
#pragma unroll
    for (int g = 0; g < 4; ++g) {
        const int row = (g << 7) | (w << 4) | m;
#pragma unroll
        for (int kt = 0; kt < 2; ++kt) {
            const float* src = W_ih + row * II + 32 * kt + 8 * grp;
            const float4 v0 = reinterpret_cast<const float4*>(src)[0];
            const float4 v1 = reinterpret_cast<const float4*>(src)[1];
            f16x8 f;
            f[0] = (_Float16)v0.x; f[1] = (_Float16)v0.y;
            f[2] = (_Float16)v0.z; f[3] = (_Float16)v0.w;
            f[4] = (_Float16)v1.x; f[5] = (_Float16)v1.y;
            f[6] = (_Float16)v1.z; f[7] = (_Float16)v1.w;
            wfx[g][kt] = f;
        }
#pragma unroll
        for (int kt = 0; kt < 4; ++kt) {
            const float* src = W_hh + row * HH + 32 * kt + 8 * grp;
            const float4 v0 = reinterpret_cast<const float4*>(src)[0];
            const float4 v1 = reinterpret_cast<const float4*>(src)[1];
            f16x8 f;
            f[0] = (_Float16)v0.x; f[1] = (_Float16)v0.y;
            f[2] = (_Float16)v0.z; f[3] = (_Float16)v0.w;
            f[4] = (_Float16)v1.x; f[5] = (_Float16)v1.y;
            f[6] = (_Float16)v1.z; f[7] = (_Float16)v1.w;
            wfh[g][kt] = f;
        }
    }

    // ---- bias scalars for the owned rows (added post-select; saves 12 VGPR
    // vs f32x4 accumulator seeding) ----
    float bs[4];
#pragma unroll
    for (int g = 0; g < 4; ++g)
        bs[g] = b_ih[(g << 7) | jown] + b_hh[(g << 7) | jown];

    // ---- state init ----
    float c = c0[(size_t)b * HH + jown];   // redundant across 4 column-copies
    if (tid < 64) {
        float2 hv = reinterpret_cast<const float2*>(h0 + (size_t)b * HH)[tid];
        s_h[0][tid] = mkh2(hv.x, hv.y);
    }

    // ---- x prefetch ring: threads 0..31 hold 4 future float2 of x ----
    // Prologue stages x0 -> s_x[0], x1 -> s_x[1]; regs then hold x2..x5.
    const float2* xin = reinterpret_cast<const float2*>(input) + (size_t)b * TT * 32 + tid;
    float2 xb0, xb1, xb2, xb3;
    if (tid < 32) {
        xb0 = xin[(size_t)0 * 32];
        xb1 = xin[(size_t)1 * 32];
        xb2 = xin[(size_t)2 * 32];
        xb3 = xin[(size_t)3 * 32];
        s_x[0][tid] = mkh2(xb0.x, xb0.y);
        s_x[1][tid] = mkh2(xb1.x, xb1.y);
        xb0 = xin[(size_t)4 * 32];   // x4
        xb1 = xin[(size_t)5 * 32];   // x5
    }
    __syncthreads();

    // ---- prologue: acc = W_ih * x_0  (bias added post-select) ----
    f32x4 acc[4];
    {
        const char* xbp = reinterpret_cast<const char*>(s_x[0]) + 16 * grp;
        f16x8 xf0 = ld_frag(xbp), xf1 = ld_frag(xbp + 64);
#pragma unroll
        for (int g = 0; g < 4; ++g) {
            f32x4 z = {0.f, 0.f, 0.f, 0.f};
            z = __builtin_amdgcn_mfma_f32_16x16x32_f16(wfx[g][0], xf0, z, 0, 0, 0);
            acc[g] = __builtin_amdgcn_mfma_f32_16x16x32_f16(wfx[g][1], xf1, z, 0, 0, 0);
        }
    }

    float* out_h = out;            // [B*H]
    float* out_e = out + BB * HH;  // [B*T*H]
    float hlast = 0.0f;
    const bool writer = (lane & 12) == 0;    // one lane per owned j

    auto step = [&](int t, float2& xbn) {
        const int cb = t & 1, nb = cb ^ 1;

        // stage x_{t+2} into ring slot (t+2)%3; refetch x_{t+6}
        if (tid < 32) {
            s_x[(t + 2) % 3][tid] = mkh2(xbn.x, xbn.y);
            int tn = t + 6; if (tn > TT - 1) tn = TT - 1;   // clamped, harmless
            xbn = xin[(size_t)tn * 32];
        }

        // ---- critical path: W_hh * h_t ----
        const char* hb = reinterpret_cast<const char*>(s_h[cb]) + 16 * grp;
        f16x8 hf0 = ld_frag(hb);
        f16x8 hf1 = ld_frag(hb + 64);
        f16x8 hf2 = ld_frag(hb + 128);
        f16x8 hf3 = ld_frag(hb + 192);
#pragma unroll
        for (int g = 0; g < 4; ++g)
            acc[g] = __builtin_amdgcn_mfma_f32_16x16x32_f16(wfh[g][0], hf0, acc[g], 0, 0, 0);
#pragma unroll
        for (int g = 0; g < 4; ++g)
            acc[g] = __builtin_amdgcn_mfma_f32_16x16x32_f16(wfh[g][1], hf1, acc[g], 0, 0, 0);
#pragma unroll
        for (int g = 0; g < 4; ++g)
            acc[g] = __builtin_amdgcn_mfma_f32_16x16x32_f16(wfh[g][2], hf2, acc[g], 0, 0, 0);
#pragma unroll
        for (int g = 0; g < 4; ++g)
            acc[g] = __builtin_amdgcn_mfma_f32_16x16x32_f16(wfh[g][3], hf3, acc[g], 0, 0, 0);

        // ---- select owned accumulator element (frees acc) ----
        const bool s1 = (lane & 1) != 0, s2 = (lane & 2) != 0;
        float p0 = s2 ? (s1 ? acc[0][3] : acc[0][2]) : (s1 ? acc[0][1] : acc[0][0]);
        float p1 = s2 ? (s1 ? acc[1][3] : acc[1][2]) : (s1 ? acc[1][1] : acc[1][0]);
        float p2 = s2 ? (s1 ? acc[2][3] : acc[2][2]) : (s1 ? acc[2][1] : acc[2][0]);
        float p3 = s2 ? (s1 ? acc[3][3] : acc[3][2]) : (s1 ? acc[3][1] : acc[3][0]);

        // ---- off-critical: reseed acc with W_ih * x_{t+1} (overlaps the
        // activation chain below; only gated by the select's anti-dep) ----
        {
            const char* xbp = reinterpret_cast<const char*>(s_x[(t + 1) % 3]) + 16 * grp;
            f16x8 xf0 = ld_frag(xbp), xf1 = ld_frag(xbp + 64);
#pragma unroll
            for (int g = 0; g < 4; ++g) {
                f32x4 z = {0.f, 0.f, 0.f, 0.f};
                z = __builtin_amdgcn_mfma_f32_16x16x32_f16(wfx[g][0], xf0, z, 0, 0, 0);
                acc[g] = __builtin_amdgcn_mfma_f32_16x16x32_f16(wfx[g][1], xf1, z, 0, 0, 0);
            }
        }

        // ---- activations (VALU, overlapped with x-MFMAs above) ----
        float ig = sigmoid_fast(p0 + bs[0]);
        float fg = sigmoid_fast(p1 + bs[1]);
        float gg = tanh_fast(p2 + bs[2]);
        float og = sigmoid_fast(p3 + bs[3]);

        c = fmaf(fg, c, ig * gg);
        float hv = og * tanh_fast(c);
        hlast = hv;

        if (writer) {
            reinterpret_cast<_Float16*>(s_h[nb])[jown] = (_Float16)hv;
            out_e[((size_t)b * TT + t) * HH + jown] = hv;
        }

        __syncthreads();
    };

    for (int t0 = 0; t0 < TT; t0 += 4) {
        step(t0 + 0, xb2);
        step(t0 + 1, xb3);
        step(t0 + 2, xb0);
        step(t0 + 3, xb1);
    }

    if (writer) out_h[(size_t)b * HH + jown] = hlast;
}

extern "C" void kernel_launch(void* const* d_in, const int* in_sizes, int n_in,
                              void* d_out, int out_size, void* d_ws, size_t ws_size,
                              hipStream_t stream) {
    const float* input = (const float*)d_in[0];
    const float* h0    = (const float*)d_in[1];
    const float* c0    = (const float*)d_in[2];
    const float* W_ih  = (const float*)d_in[3];
    const float* W_hh  = (const float*)d_in[4];
    const float* b_ih  = (const float*)d_in[5];
    const float* b_hh  = (const float*)d_in[6];
    float* out = (float*)d_out;

    hipLaunchKernelGGL(lstm_fused_kernel, dim3(BB), dim3(512), 0, stream,
                       input, h0, c0, W_ih, W_hh, b_ih, b_hh, out);
}